// Round 12
// baseline (169.289 us; speedup 1.0000x reference)
//
#include <hip/hip_runtime.h>
#include <stdint.h>

// R12: k2 main loop goes LDS-free. Evidence trail: the LDS-staged design has
// a ~15 us per-CU LDS-issue floor (each wave re-reads the whole 16 KB Bs
// every chunk; 16 waves x 28 LDS instr x ~11 cyc x 8 chunks), which matches
// the observed k2 ~30 us >> MFMA work (~3 us). Fix: both operands load
// straight from global to VGPRs — A as a 16-rows x 64B gather per window
// pair (s,e2) with fmax in registers, B from the 128 KB L2-resident w1t.
// No barriers, no ds_read/ds_write, waves independent; the <=2-level tile
// constraint disappears (direct level addressing).

typedef unsigned short u16;
typedef unsigned int u32;

#define B_    32
#define S_    64
#define H_    512
#define ATT_  128
#define NWIN  2016
#define NLEV  7
#define TLEV  6   // stored levels: 1..6

typedef __bf16 bf16x8 __attribute__((ext_vector_type(8)));
typedef float  f32x4  __attribute__((ext_vector_type(4)));

__device__ __forceinline__ float asf(u32 i) {
  union { u32 i; float f; } v; v.i = i; return v.f;
}
__device__ __forceinline__ u32 asu(float f) {
  union { float f; u32 i; } v; v.f = f; return v.i;
}
__device__ __forceinline__ float bf2f(u16 u) { return asf(((u32)u) << 16); }
__device__ __forceinline__ u16 f2bf(float f) {
  u32 i = asu(f);
  i += 0x7fffu + ((i >> 16) & 1u);   // round-to-nearest-even
  return (u16)(i >> 16);
}
// Exact bf16x2 max: halves viewed as f32 (low mantissa zero) -> v_max_f32
// exact; repack high halves. bf16 rounding is monotone, so the bf16 sparse
// table introduces no extra error vs rounding the pooled values.
__device__ __forceinline__ u32 bfmax2(u32 a, u32 b) {
  float a0 = asf(a << 16), a1 = asf(a & 0xffff0000u);
  float b0 = asf(b << 16), b1 = asf(b & 0xffff0000u);
  u32 m0 = asu(fmaxf(a0, b0)), m1 = asu(fmaxf(a1, b1));
  return (m1 & 0xffff0000u) | (m0 >> 16);
}
__device__ __forceinline__ uint4 bfmax8(uint4 a, uint4 b) {
  uint4 m;
  m.x = bfmax2(a.x, b.x); m.y = bfmax2(a.y, b.y);
  m.z = bfmax2(a.z, b.z); m.w = bfmax2(a.w, b.w);
  return m;
}
__device__ __forceinline__ bf16x8 as_bf16x8(uint4 v) {
  union { uint4 u; bf16x8 h; } c; c.u = v; return c.h;
}

// ============ k01: sparse table build + widx + W1^T (one launch) ============
// blocks [0,256): per-(hc,b) 64-column slab; level 0 stays in LDS only,
// levels 1..6 stream to global (level L at offset (L-1)*S*H).
// blocks [256,288): W1^T -> bf16 transpose; block 256 additionally emits widx.
__launch_bounds__(256)
__global__ void k01_init(const float* __restrict__ lstm, const float* __restrict__ W1,
                         u16* __restrict__ table, u16* __restrict__ w1t,
                         u16* __restrict__ widx) {
  int bid = blockIdx.x, tid = threadIdx.x;
  __shared__ u16 bufA[64 * 64], bufB[64 * 64];
  if (bid < 256) {
    int hc = bid & 7, b = bid >> 3;
    const float* src = lstm + (size_t)b * S_ * H_ + hc * 64;
    u16* tb = table + (size_t)b * TLEV * S_ * H_ + hc * 64;
    // level 0: fp32 -> bf16 into LDS only (never read from global)
    for (int t = tid; t < 64 * 16; t += 256) {
      int r = t >> 4, c4 = t & 15;
      float4 f = *reinterpret_cast<const float4*>(src + r * H_ + c4 * 4);
      ushort4 u;
      u.x = f2bf(f.x); u.y = f2bf(f.y); u.z = f2bf(f.z); u.w = f2bf(f.w);
      *reinterpret_cast<ushort4*>(&bufA[r * 64 + c4 * 4]) = u;
    }
    u16* pa = bufA; u16* pb = bufB;
    for (int k = 1; k < NLEV; ++k) {
      __syncthreads();
      int half = 1 << (k - 1);
      u16* dst_g = tb + (size_t)(k - 1) * S_ * H_;
      for (int t = tid; t < 64 * 16; t += 256) {
        int r = t >> 4, c4 = t & 15;
        int r2 = r + half; if (r2 > 63) r2 = 63;  // replicated tail, never read
        uint2 a  = *reinterpret_cast<const uint2*>(&pa[r  * 64 + c4 * 4]);
        uint2 bq = *reinterpret_cast<const uint2*>(&pa[r2 * 64 + c4 * 4]);
        uint2 m; m.x = bfmax2(a.x, bq.x); m.y = bfmax2(a.y, bq.y);
        *reinterpret_cast<uint2*>(&pb[r * 64 + c4 * 4]) = m;
        *reinterpret_cast<uint2*>(dst_g + r * H_ + c4 * 4) = m;
      }
      u16* tmp = pa; pa = pb; pb = tmp;
    }
  } else {
    int gb = bid - 256;   // 0..31
    if (gb == 0) {
      for (int n = tid; n < NWIN; n += 256) {
        int w = 2, rem = n;
        while (rem >= 65 - w) { rem -= 65 - w; ++w; }
        int s = rem;
        int k = 31 - __clz(w);
        int e2 = s + w - (1 << k);
        widx[n] = (u16)(s | (e2 << 6) | (k << 12));
      }
    }
    for (int q = tid; q < 2048; q += 256) {
      int idx = gb * 2048 + q;
      int n = idx >> 9, kq = idx & 511;
      w1t[idx] = f2bf(W1[kq * ATT_ + n]);
    }
  }
}

// ====== k2: pooled @ W1 (MFMA bf16) + bias + relu + @W2 -> scores ==========
// grid (32, 32), 256 thr. Tile: 64 windows x 128 att, K=512 in 8 chunks of 64.
// Wave grid 4x1 in M: wave w owns windows [16w,16w+16) x all 128 att.
// LDS-free main loop: per chunk, lane (lrow,quad) gathers its window's two
// table rows (s,e2) at column kk + k2i*32 + quad*8 (wave pattern: 16 rows x
// 64 contiguous bytes), fmaxes in registers -> A-frag; B-frags load directly
// from the L2-resident 128 KB w1t. 20 global loads + 16 MFMAs per chunk,
// zero barriers after the widx/bias preamble.
__launch_bounds__(256)
__attribute__((amdgpu_waves_per_eu(1, 4)))
__global__ void k2_scores(const u16* __restrict__ table, const u16* __restrict__ w1t,
                          const float* __restrict__ b1, const float* __restrict__ w2,
                          const u16* __restrict__ widx, float* __restrict__ scores) {
  const int b = blockIdx.y, mt = blockIdx.x;
  __shared__ u16 widx_l[64];
  __shared__ float b1s[128], w2s[128];
  int tid = threadIdx.x;
  if (tid < 64) {
    int n = mt * 64 + tid; if (n > NWIN - 1) n = NWIN - 1;  // pad-clamp
    widx_l[tid] = widx[n];
  }
  if (tid < 128) { b1s[tid] = b1[tid]; w2s[tid] = w2[tid]; }
  __syncthreads();

  const u16* tbB = table + (size_t)b * TLEV * S_ * H_;   // level L at (L-1)*S*H

  int wid = tid >> 6, lane = tid & 63;
  int lrow = lane & 15, quad = lane >> 4;

  // this wave's window for all its A-fragments: m = wid*16 + lrow
  int pk = widx_l[wid * 16 + lrow];
  int s = pk & 63, e2 = (pk >> 6) & 63, lv = pk >> 12;   // lv in 1..6
  const u16* aS = tbB + (size_t)((lv - 1) * S_ + s)  * H_ + quad * 8;
  const u16* aE = tbB + (size_t)((lv - 1) * S_ + e2) * H_ + quad * 8;
  // B base pointers: frag j covers att rows j*16+lrow
  const u16* bp[8];
#pragma unroll
  for (int j = 0; j < 8; ++j) bp[j] = w1t + (j * 16 + lrow) * H_ + quad * 8;

  f32x4 acc[8];
#pragma unroll
  for (int j = 0; j < 8; ++j) acc[j] = (f32x4){0.f, 0.f, 0.f, 0.f};

  for (int kc = 0; kc < 8; ++kc) {
    int kk = kc * 64;
    uint4 as0 = *reinterpret_cast<const uint4*>(aS + kk);
    uint4 ae0 = *reinterpret_cast<const uint4*>(aE + kk);
    uint4 as1 = *reinterpret_cast<const uint4*>(aS + kk + 32);
    uint4 ae1 = *reinterpret_cast<const uint4*>(aE + kk + 32);
    bf16x8 af0 = as_bf16x8(bfmax8(as0, ae0));
    bf16x8 af1 = as_bf16x8(bfmax8(as1, ae1));
#pragma unroll
    for (int j = 0; j < 8; ++j) {
      bf16x8 b0 = *reinterpret_cast<const bf16x8*>(bp[j] + kk);
      bf16x8 b1v = *reinterpret_cast<const bf16x8*>(bp[j] + kk + 32);
      acc[j] = __builtin_amdgcn_mfma_f32_16x16x32_bf16(af0, b0, acc[j], 0, 0, 0);
      acc[j] = __builtin_amdgcn_mfma_f32_16x16x32_bf16(af1, b1v, acc[j], 0, 0, 0);
    }
  }

  // epilogue: score[m] = sum_n relu(hid+b1)*w2 (b2 dropped: softmax-invariant)
  // C layout: row = quad*4 + r, col = lrow. Reduce over 128 cols = 8 j-frags
  // in-register + 16-lane shfl; lane lrow==0 stores row quad*4+r directly.
#pragma unroll
  for (int r = 0; r < 4; ++r) {
    float p = 0.f;
#pragma unroll
    for (int j = 0; j < 8; ++j) {
      int n = j * 16 + lrow;
      float v = acc[j][r] + b1s[n];
      p += (v > 0.f ? v : 0.f) * w2s[n];
    }
    p += __shfl_xor(p, 1, 16);
    p += __shfl_xor(p, 2, 16);
    p += __shfl_xor(p, 4, 16);
    p += __shfl_xor(p, 8, 16);
    if (lrow == 0) {
      int nw = mt * 64 + wid * 16 + quad * 4 + r;
      if (nw < NWIN) scores[b * NWIN + nw] = p;
    }
  }
}

// ========= k34: per-block softmax (redundant) + attn-weighted sum ==========
// grid (16, 32), 256 thr; 32-wide h slice per block. Softmax recomputed
// per block from scores (8 exp/thread + two wave reductions); 1/sum folded
// into the final store. Table holds levels 1..6.
__launch_bounds__(256)
__global__ void k34_out(const u16* __restrict__ table, const float* __restrict__ scores,
                        const u16* __restrict__ widx, float* __restrict__ out) {
  int hc = blockIdx.x, b = blockIdx.y, tid = threadIdx.x;
  __shared__ u16 Tl[6 * 64 * 32];       // 24 KB: levels 1..6, 32-col slice
  __shared__ float attn_l[NWIN];        // 8 KB, unnormalized exp
  __shared__ u16 widx_l[NWIN];          // 4 KB
  __shared__ float red[8][32];
  __shared__ float wredM[4], wredS[4];
  const u16* tb = table + (size_t)b * TLEV * S_ * H_;   // levels 1..6
  int h0 = hc * 32;
  int lane = tid & 63, wid = tid >> 6;

  for (int t = tid; t < 6 * 64 * 4; t += 256) {
    int row = t >> 2, c = t & 3;
    uint4 v = *reinterpret_cast<const uint4*>(tb + row * H_ + h0 + c * 8);
    *reinterpret_cast<uint4*>(&Tl[row * 32 + c * 8]) = v;
  }
  for (int n = tid; n < NWIN; n += 256) widx_l[n] = widx[n];

  float mx = -1e30f;
  for (int n = tid; n < NWIN; n += 256) {
    float v = scores[b * NWIN + n];
    attn_l[n] = v;
    mx = fmaxf(mx, v);
  }
#pragma unroll
  for (int off = 32; off > 0; off >>= 1) mx = fmaxf(mx, __shfl_xor(mx, off, 64));
  if (lane == 0) wredM[wid] = mx;
  __syncthreads();   // also covers the Tl / widx_l / attn_l staging above
  mx = fmaxf(fmaxf(wredM[0], wredM[1]), fmaxf(wredM[2], wredM[3]));
  float sum = 0.f;
  for (int n = tid; n < NWIN; n += 256) {
    float e = __expf(attn_l[n] - mx);
    attn_l[n] = e;
    sum += e;
  }
#pragma unroll
  for (int off = 32; off > 0; off >>= 1) sum += __shfl_xor(sum, off, 64);
  if (lane == 0) wredS[wid] = sum;
  __syncthreads();
  float inv = 1.f / (wredS[0] + wredS[1] + wredS[2] + wredS[3]);

  int h = tid & 31, g = tid >> 5;   // 8 groups x 252 windows each
  float acc = 0.f;
  for (int n = g * 252; n < g * 252 + 252; ++n) {
    int pk = widx_l[n];
    int s = pk & 63, e2 = (pk >> 6) & 63, lv = pk >> 12;
    float va = bf2f(Tl[((lv - 1) * 64 + s) * 32 + h]);
    float vb = bf2f(Tl[((lv - 1) * 64 + e2) * 32 + h]);
    acc += attn_l[n] * fmaxf(va, vb);
  }
  red[g][h] = acc;
  __syncthreads();
  if (tid < 32) {
    float s2 = 0.f;
#pragma unroll
    for (int g2 = 0; g2 < 8; ++g2) s2 += red[g2][tid];
    out[b * H_ + h0 + tid] = s2 * inv;
  }
}

// ================================ launch ===================================
extern "C" void kernel_launch(void* const* d_in, const int* in_sizes, int n_in,
                              void* d_out, int out_size, void* d_ws, size_t ws_size,
                              hipStream_t stream) {
  const float* lstm = (const float*)d_in[0];
  const float* W1   = (const float*)d_in[1];
  const float* b1   = (const float*)d_in[2];
  const float* W2   = (const float*)d_in[3];
  // d_in[4] = b2: uniform shift ahead of softmax -> no output effect, unused.
  float* out = (float*)d_out;

  char* ws = (char*)d_ws;
  // ws layout: widx u16 [0,4096) | w1t bf16 [4096,135168)
  //            | table bf16 levels 1..6 (12.58 MB) | scores f32 (258048 B)
  u16*   widx   = (u16*)(ws + 0);
  u16*   w1t    = (u16*)(ws + 4096);
  u16*   table  = (u16*)(ws + 135168);
  float* scores = (float*)(ws + 12718080);

  k01_init <<<288, 256, 0, stream>>>(lstm, W1, table, w1t, widx);
  k2_scores<<<dim3(32, B_), 256, 0, stream>>>(table, w1t, b1, W2, widx, scores);
  k34_out  <<<dim3(16, B_), 256, 0, stream>>>(table, scores, widx, out);
}

// Round 13
// 138.779 us; speedup vs baseline: 1.2198x; 1.2198x over previous
//
#include <hip/hip_runtime.h>
#include <stdint.h>

// R13: B operand leaves LDS entirely. R12 proved direct per-lane fragment
// gathers are the killer (uncoalesced: 64 cache lines per load, k2=75us);
// R11 proved LDS staging works but pays 28 LDS instr/wave/chunk. Fix: k01
// emits w1t in FRAGMENT-MAJOR order (w1tf), so every B-frag is a perfectly
// coalesced 1KB wave load from the L2-resident 128KB constant — no LDS, no
// transpose at use. A keeps R11's slab staging (its (s,e2) gather needs the
// LDS transform). LDS instr/wave/chunk: 28 -> 8; LDS 33 -> 17.5 KB.

typedef unsigned short u16;
typedef unsigned int u32;

#define B_    32
#define S_    64
#define H_    512
#define ATT_  128
#define NWIN  2016
#define NLEV  7
#define TLEV  6   // stored levels: 1..6

typedef __bf16 bf16x8 __attribute__((ext_vector_type(8)));
typedef float  f32x4  __attribute__((ext_vector_type(4)));

__device__ __forceinline__ float asf(u32 i) {
  union { u32 i; float f; } v; v.i = i; return v.f;
}
__device__ __forceinline__ u32 asu(float f) {
  union { float f; u32 i; } v; v.f = f; return v.i;
}
__device__ __forceinline__ float bf2f(u16 u) { return asf(((u32)u) << 16); }
__device__ __forceinline__ u16 f2bf(float f) {
  u32 i = asu(f);
  i += 0x7fffu + ((i >> 16) & 1u);   // round-to-nearest-even
  return (u16)(i >> 16);
}
// Exact bf16x2 max: halves viewed as f32 (low mantissa zero) -> v_max_f32
// exact; repack high halves. bf16 rounding is monotone, so the bf16 sparse
// table introduces no extra error vs rounding the pooled values.
__device__ __forceinline__ u32 bfmax2(u32 a, u32 b) {
  float a0 = asf(a << 16), a1 = asf(a & 0xffff0000u);
  float b0 = asf(b << 16), b1 = asf(b & 0xffff0000u);
  u32 m0 = asu(fmaxf(a0, b0)), m1 = asu(fmaxf(a1, b1));
  return (m1 & 0xffff0000u) | (m0 >> 16);
}
__device__ __forceinline__ uint4 bfmax8(uint4 a, uint4 b) {
  uint4 m;
  m.x = bfmax2(a.x, b.x); m.y = bfmax2(a.y, b.y);
  m.z = bfmax2(a.z, b.z); m.w = bfmax2(a.w, b.w);
  return m;
}
__device__ __forceinline__ bf16x8 as_bf16x8(uint4 v) {
  union { uint4 u; bf16x8 h; } c; c.u = v; return c.h;
}

// ============ k01: sparse table build + widx + W1 frag-major (one launch) ===
// blocks [0,256): per-(hc,b) 64-column slab; level 0 stays in LDS only,
// levels 1..6 stream to global (level L at offset (L-1)*S*H).
// blocks [256,288): w1tf fragment-major emit; block 256 additionally emits
// widx. w1tf flat index idx encodes: e=idx&7, L=(idx>>3)&63, j=(idx>>9)&7,
// k2i=(idx>>12)&1, kc=idx>>13; value = W1[kq*128+n] with n=j*16+(L&15),
// kq = kc*64 + k2i*32 + (L>>4)*8 + e. A B-frag load in k2 is then the
// contiguous 1KB slab idx in [(kc*16+k2i*8+j)*512, +512).
__launch_bounds__(256)
__global__ void k01_init(const float* __restrict__ lstm, const float* __restrict__ W1,
                         u16* __restrict__ table, u16* __restrict__ w1tf,
                         u16* __restrict__ widx) {
  int bid = blockIdx.x, tid = threadIdx.x;
  __shared__ u16 bufA[64 * 64], bufB[64 * 64];
  if (bid < 256) {
    int hc = bid & 7, b = bid >> 3;
    const float* src = lstm + (size_t)b * S_ * H_ + hc * 64;
    u16* tb = table + (size_t)b * TLEV * S_ * H_ + hc * 64;
    // level 0: fp32 -> bf16 into LDS only (never read from global)
    for (int t = tid; t < 64 * 16; t += 256) {
      int r = t >> 4, c4 = t & 15;
      float4 f = *reinterpret_cast<const float4*>(src + r * H_ + c4 * 4);
      ushort4 u;
      u.x = f2bf(f.x); u.y = f2bf(f.y); u.z = f2bf(f.z); u.w = f2bf(f.w);
      *reinterpret_cast<ushort4*>(&bufA[r * 64 + c4 * 4]) = u;
    }
    u16* pa = bufA; u16* pb = bufB;
    for (int k = 1; k < NLEV; ++k) {
      __syncthreads();
      int half = 1 << (k - 1);
      u16* dst_g = tb + (size_t)(k - 1) * S_ * H_;
      for (int t = tid; t < 64 * 16; t += 256) {
        int r = t >> 4, c4 = t & 15;
        int r2 = r + half; if (r2 > 63) r2 = 63;  // replicated tail, never read
        uint2 a  = *reinterpret_cast<const uint2*>(&pa[r  * 64 + c4 * 4]);
        uint2 bq = *reinterpret_cast<const uint2*>(&pa[r2 * 64 + c4 * 4]);
        uint2 m; m.x = bfmax2(a.x, bq.x); m.y = bfmax2(a.y, bq.y);
        *reinterpret_cast<uint2*>(&pb[r * 64 + c4 * 4]) = m;
        *reinterpret_cast<uint2*>(dst_g + r * H_ + c4 * 4) = m;
      }
      u16* tmp = pa; pa = pb; pb = tmp;
    }
  } else {
    int gb = bid - 256;   // 0..31
    if (gb == 0) {
      for (int n = tid; n < NWIN; n += 256) {
        int w = 2, rem = n;
        while (rem >= 65 - w) { rem -= 65 - w; ++w; }
        int s = rem;
        int k = 31 - __clz(w);
        int e2 = s + w - (1 << k);
        widx[n] = (u16)(s | (e2 << 6) | (k << 12));
      }
    }
    for (int q = tid; q < 2048; q += 256) {
      int idx = gb * 2048 + q;
      int e = idx & 7, L = (idx >> 3) & 63, j = (idx >> 9) & 7;
      int k2i = (idx >> 12) & 1, kc = idx >> 13;
      int n  = j * 16 + (L & 15);
      int kq = kc * 64 + k2i * 32 + (L >> 4) * 8 + e;
      w1tf[idx] = f2bf(W1[kq * ATT_ + n]);
    }
  }
}

// ====== k2: pooled @ W1 (MFMA bf16) + bias + relu + @W2 -> scores ==========
// grid (32, 32), 256 thr. Tile: 64 windows x 128 att, K=512 in 8 chunks of 64.
// Wave grid 4x1 in M: wave w owns windows [16w,16w+16) x all 128 att.
// A: R11 slab staging (coalesced global -> swizzled LDS, register prefetch-1;
// a 64-window tile spans <=2 adjacent levels). B: direct coalesced 1KB wave
// loads from fragment-major w1tf (L2-resident) — zero LDS for B.
__launch_bounds__(256)
__attribute__((amdgpu_waves_per_eu(1, 4)))
__global__ void k2_scores(const u16* __restrict__ table, const u16* __restrict__ w1tf,
                          const float* __restrict__ b1, const float* __restrict__ w2,
                          const u16* __restrict__ widx, float* __restrict__ scores) {
  const int b = blockIdx.y, mt = blockIdx.x;
  __shared__ u16 Ts[128 * 64];   // two level slabs, swizzled, 16 KB
  __shared__ u16 widx_l[64];
  __shared__ float b1s[128], w2s[128];
  int tid = threadIdx.x;
  if (tid < 64) {
    int n = mt * 64 + tid; if (n > NWIN - 1) n = NWIN - 1;  // pad-clamp
    widx_l[tid] = widx[n];
  }
  if (tid < 128) { b1s[tid] = b1[tid]; w2s[tid] = w2[tid]; }
  __syncthreads();

  const int lv_lo = widx_l[0] >> 12;   // tile's lowest level (>=1); max lv_lo+1
  const u16* tb = table + (size_t)b * TLEV * S_ * H_ + (size_t)(lv_lo - 1) * S_ * H_;

  // Ts staging slots (1024 tasks / 256 thr = 4): t = tid + i*256,
  // row = t>>3 in 0..127, c = t&7; swizzled dst = row*64 + ((c^(row&7))*8)
  int t0 = tid, t1 = tid + 256, t2 = tid + 512, t3 = tid + 768;
  int r0 = t0 >> 3, r1 = t1 >> 3, r2 = t2 >> 3, r3 = t3 >> 3;
  int c0 = t0 & 7,  c1 = t1 & 7,  c2 = t2 & 7,  c3 = t3 & 7;
  const u16* ts0 = tb + r0 * H_ + c0 * 8;
  const u16* ts1 = tb + r1 * H_ + c1 * 8;
  const u16* ts2 = tb + r2 * H_ + c2 * 8;
  const u16* ts3 = tb + r3 * H_ + c3 * 8;
  int sd0 = r0 * 64 + ((c0 ^ (r0 & 7)) * 8);
  int sd1 = r1 * 64 + ((c1 ^ (r1 & 7)) * 8);
  int sd2 = r2 * 64 + ((c2 ^ (r2 & 7)) * 8);
  int sd3 = r3 * 64 + ((c3 ^ (r3 & 7)) * 8);

  int wid = tid >> 6, lane = tid & 63;
  int lrow = lane & 15, quad = lane >> 4;

  // A-fragment addresses: this wave's window m = wid*16 + lrow; {s,e2} x k2i
  int aoff[2][2];
  {
    int pk = widx_l[wid * 16 + lrow];
    int s = pk & 63, e2 = (pk >> 6) & 63, lv = (pk >> 12) - lv_lo;  // 0 or 1
    int rs = lv * 64 + s, re = lv * 64 + e2;
#pragma unroll
    for (int k2i = 0; k2i < 2; ++k2i) {
      int c = quad + k2i * 4;
      aoff[k2i][0] = rs * 64 + ((c ^ (rs & 7)) * 8);
      aoff[k2i][1] = re * 64 + ((c ^ (re & 7)) * 8);
    }
  }
  // B base: frag (kc,k2i,j) lives at w1tf + (kc*16 + k2i*8 + j)*512 + lane*8
  const u16* wb = w1tf + lane * 8;

  uint4 rT0, rT1, rT2, rT3;

#define ISSUE(KK) do { \
  rT0 = *reinterpret_cast<const uint4*>(ts0 + (KK)); \
  rT1 = *reinterpret_cast<const uint4*>(ts1 + (KK)); \
  rT2 = *reinterpret_cast<const uint4*>(ts2 + (KK)); \
  rT3 = *reinterpret_cast<const uint4*>(ts3 + (KK)); \
} while (0)

#define STAGE() do { \
  *reinterpret_cast<uint4*>(&Ts[sd0]) = rT0; \
  *reinterpret_cast<uint4*>(&Ts[sd1]) = rT1; \
  *reinterpret_cast<uint4*>(&Ts[sd2]) = rT2; \
  *reinterpret_cast<uint4*>(&Ts[sd3]) = rT3; \
} while (0)

  ISSUE(0);

  f32x4 acc[8];
#pragma unroll
  for (int j = 0; j < 8; ++j) acc[j] = (f32x4){0.f, 0.f, 0.f, 0.f};

  for (int kc = 0; kc < 8; ++kc) {
    __syncthreads();   // previous chunk's A-frag reads complete
    STAGE();
    __syncthreads();
    if (kc < 7) ISSUE((kc + 1) * 64);   // hides under the MFMA chunk below
#pragma unroll
    for (int k2i = 0; k2i < 2; ++k2i) {
      uint4 va = *reinterpret_cast<const uint4*>(&Ts[aoff[k2i][0]]);
      uint4 vb = *reinterpret_cast<const uint4*>(&Ts[aoff[k2i][1]]);
      bf16x8 af = as_bf16x8(bfmax8(va, vb));
      const u16* wbk = wb + (kc * 16 + k2i * 8) * 512;
#pragma unroll
      for (int j = 0; j < 8; ++j) {
        bf16x8 bfr = *reinterpret_cast<const bf16x8*>(wbk + j * 512);
        acc[j] = __builtin_amdgcn_mfma_f32_16x16x32_bf16(af, bfr, acc[j], 0, 0, 0);
      }
    }
  }

#undef ISSUE
#undef STAGE

  // epilogue: score[m] = sum_n relu(hid+b1)*w2 (b2 dropped: softmax-invariant)
  // C layout: row = quad*4 + r, col = lrow. Reduce over 128 cols = 8 j-frags
  // in-register + 16-lane shfl; lane lrow==0 stores row quad*4+r directly.
#pragma unroll
  for (int r = 0; r < 4; ++r) {
    float p = 0.f;
#pragma unroll
    for (int j = 0; j < 8; ++j) {
      int n = j * 16 + lrow;
      float v = acc[j][r] + b1s[n];
      p += (v > 0.f ? v : 0.f) * w2s[n];
    }
    p += __shfl_xor(p, 1, 16);
    p += __shfl_xor(p, 2, 16);
    p += __shfl_xor(p, 4, 16);
    p += __shfl_xor(p, 8, 16);
    if (lrow == 0) {
      int nw = mt * 64 + wid * 16 + quad * 4 + r;
      if (nw < NWIN) scores[b * NWIN + nw] = p;
    }
  }
}

// ========= k34: per-block softmax (redundant) + attn-weighted sum ==========
// grid (16, 32), 256 thr; 32-wide h slice per block. Softmax recomputed
// per block from scores (8 exp/thread + two wave reductions); 1/sum folded
// into the final store. Table holds levels 1..6.
__launch_bounds__(256)
__global__ void k34_out(const u16* __restrict__ table, const float* __restrict__ scores,
                        const u16* __restrict__ widx, float* __restrict__ out) {
  int hc = blockIdx.x, b = blockIdx.y, tid = threadIdx.x;
  __shared__ u16 Tl[6 * 64 * 32];       // 24 KB: levels 1..6, 32-col slice
  __shared__ float attn_l[NWIN];        // 8 KB, unnormalized exp
  __shared__ u16 widx_l[NWIN];          // 4 KB
  __shared__ float red[8][32];
  __shared__ float wredM[4], wredS[4];
  const u16* tb = table + (size_t)b * TLEV * S_ * H_;   // levels 1..6
  int h0 = hc * 32;
  int lane = tid & 63, wid = tid >> 6;

  for (int t = tid; t < 6 * 64 * 4; t += 256) {
    int row = t >> 2, c = t & 3;
    uint4 v = *reinterpret_cast<const uint4*>(tb + row * H_ + h0 + c * 8);
    *reinterpret_cast<uint4*>(&Tl[row * 32 + c * 8]) = v;
  }
  for (int n = tid; n < NWIN; n += 256) widx_l[n] = widx[n];

  float mx = -1e30f;
  for (int n = tid; n < NWIN; n += 256) {
    float v = scores[b * NWIN + n];
    attn_l[n] = v;
    mx = fmaxf(mx, v);
  }
#pragma unroll
  for (int off = 32; off > 0; off >>= 1) mx = fmaxf(mx, __shfl_xor(mx, off, 64));
  if (lane == 0) wredM[wid] = mx;
  __syncthreads();   // also covers the Tl / widx_l / attn_l staging above
  mx = fmaxf(fmaxf(wredM[0], wredM[1]), fmaxf(wredM[2], wredM[3]));
  float sum = 0.f;
  for (int n = tid; n < NWIN; n += 256) {
    float e = __expf(attn_l[n] - mx);
    attn_l[n] = e;
    sum += e;
  }
#pragma unroll
  for (int off = 32; off > 0; off >>= 1) sum += __shfl_xor(sum, off, 64);
  if (lane == 0) wredS[wid] = sum;
  __syncthreads();
  float inv = 1.f / (wredS[0] + wredS[1] + wredS[2] + wredS[3]);

  int h = tid & 31, g = tid >> 5;   // 8 groups x 252 windows each
  float acc = 0.f;
  for (int n = g * 252; n < g * 252 + 252; ++n) {
    int pk = widx_l[n];
    int s = pk & 63, e2 = (pk >> 6) & 63, lv = pk >> 12;
    float va = bf2f(Tl[((lv - 1) * 64 + s) * 32 + h]);
    float vb = bf2f(Tl[((lv - 1) * 64 + e2) * 32 + h]);
    acc += attn_l[n] * fmaxf(va, vb);
  }
  red[g][h] = acc;
  __syncthreads();
  if (tid < 32) {
    float s2 = 0.f;
#pragma unroll
    for (int g2 = 0; g2 < 8; ++g2) s2 += red[g2][tid];
    out[b * H_ + h0 + tid] = s2 * inv;
  }
}

// ================================ launch ===================================
extern "C" void kernel_launch(void* const* d_in, const int* in_sizes, int n_in,
                              void* d_out, int out_size, void* d_ws, size_t ws_size,
                              hipStream_t stream) {
  const float* lstm = (const float*)d_in[0];
  const float* W1   = (const float*)d_in[1];
  const float* b1   = (const float*)d_in[2];
  const float* W2   = (const float*)d_in[3];
  // d_in[4] = b2: uniform shift ahead of softmax -> no output effect, unused.
  float* out = (float*)d_out;

  char* ws = (char*)d_ws;
  // ws layout: widx u16 [0,4096) | w1tf bf16 [4096,135168)
  //            | table bf16 levels 1..6 (12.58 MB) | scores f32 (258048 B)
  u16*   widx   = (u16*)(ws + 0);
  u16*   w1tf   = (u16*)(ws + 4096);
  u16*   table  = (u16*)(ws + 135168);
  float* scores = (float*)(ws + 12718080);

  k01_init <<<288, 256, 0, stream>>>(lstm, W1, table, w1tf, widx);
  k2_scores<<<dim3(32, B_), 256, 0, stream>>>(table, w1tf, b1, W2, widx, scores);
  k34_out  <<<dim3(16, B_), 256, 0, stream>>>(table, scores, widx, out);
}

// Round 14
// 118.066 us; speedup vs baseline: 1.4339x; 1.1754x over previous
//
#include <hip/hip_runtime.h>
#include <stdint.h>

// R14: synthesis after R12/R13 falsifications. A operand: LDS slab staging
// (layout transform needed — R12 proved direct gathers catastrophic). B
// operand: LDS staging restored (R13's direct-L2 reads amplified B traffic
// 4x: every wave re-read the chunk; LDS shares it per-block), but from the
// frag-major w1tf so both the staging copy and the ds_read_b128 fragment
// reads are fully CONTIGUOUS (conflict-free, no swizzle VALU). k34 re-grid
// (16,32)->(32,32): halves its dominant 252-window scalar loop per thread.

typedef unsigned short u16;
typedef unsigned int u32;

#define B_    32
#define S_    64
#define H_    512
#define ATT_  128
#define NWIN  2016
#define NLEV  7
#define TLEV  6   // stored levels: 1..6

typedef __bf16 bf16x8 __attribute__((ext_vector_type(8)));
typedef float  f32x4  __attribute__((ext_vector_type(4)));

__device__ __forceinline__ float asf(u32 i) {
  union { u32 i; float f; } v; v.i = i; return v.f;
}
__device__ __forceinline__ u32 asu(float f) {
  union { float f; u32 i; } v; v.f = f; return v.i;
}
__device__ __forceinline__ float bf2f(u16 u) { return asf(((u32)u) << 16); }
__device__ __forceinline__ u16 f2bf(float f) {
  u32 i = asu(f);
  i += 0x7fffu + ((i >> 16) & 1u);   // round-to-nearest-even
  return (u16)(i >> 16);
}
// Exact bf16x2 max: halves viewed as f32 (low mantissa zero) -> v_max_f32
// exact; repack high halves. bf16 rounding is monotone, so the bf16 sparse
// table introduces no extra error vs rounding the pooled values.
__device__ __forceinline__ u32 bfmax2(u32 a, u32 b) {
  float a0 = asf(a << 16), a1 = asf(a & 0xffff0000u);
  float b0 = asf(b << 16), b1 = asf(b & 0xffff0000u);
  u32 m0 = asu(fmaxf(a0, b0)), m1 = asu(fmaxf(a1, b1));
  return (m1 & 0xffff0000u) | (m0 >> 16);
}
__device__ __forceinline__ uint4 bfmax8(uint4 a, uint4 b) {
  uint4 m;
  m.x = bfmax2(a.x, b.x); m.y = bfmax2(a.y, b.y);
  m.z = bfmax2(a.z, b.z); m.w = bfmax2(a.w, b.w);
  return m;
}
__device__ __forceinline__ bf16x8 as_bf16x8(uint4 v) {
  union { uint4 u; bf16x8 h; } c; c.u = v; return c.h;
}

// ============ k01: sparse table build + widx + W1 frag-major (one launch) ===
// blocks [0,256): per-(hc,b) 64-column slab; level 0 stays in LDS only,
// levels 1..6 stream to global (level L at offset (L-1)*S*H).
// blocks [256,288): w1tf fragment-major emit; block 256 additionally emits
// widx. w1tf flat index idx: e=idx&7, L=(idx>>3)&63, j=(idx>>9)&7,
// k2i=(idx>>12)&1, kc=idx>>13; value = W1[kq*128+n], n=j*16+(L&15),
// kq = kc*64 + k2i*32 + (L>>4)*8 + e. Chunk kc = 16 KB at idx [kc*8192,+8192).
__launch_bounds__(256)
__global__ void k01_init(const float* __restrict__ lstm, const float* __restrict__ W1,
                         u16* __restrict__ table, u16* __restrict__ w1tf,
                         u16* __restrict__ widx) {
  int bid = blockIdx.x, tid = threadIdx.x;
  __shared__ u16 bufA[64 * 64], bufB[64 * 64];
  if (bid < 256) {
    int hc = bid & 7, b = bid >> 3;
    const float* src = lstm + (size_t)b * S_ * H_ + hc * 64;
    u16* tb = table + (size_t)b * TLEV * S_ * H_ + hc * 64;
    // level 0: fp32 -> bf16 into LDS only (never read from global)
    for (int t = tid; t < 64 * 16; t += 256) {
      int r = t >> 4, c4 = t & 15;
      float4 f = *reinterpret_cast<const float4*>(src + r * H_ + c4 * 4);
      ushort4 u;
      u.x = f2bf(f.x); u.y = f2bf(f.y); u.z = f2bf(f.z); u.w = f2bf(f.w);
      *reinterpret_cast<ushort4*>(&bufA[r * 64 + c4 * 4]) = u;
    }
    u16* pa = bufA; u16* pb = bufB;
    for (int k = 1; k < NLEV; ++k) {
      __syncthreads();
      int half = 1 << (k - 1);
      u16* dst_g = tb + (size_t)(k - 1) * S_ * H_;
      for (int t = tid; t < 64 * 16; t += 256) {
        int r = t >> 4, c4 = t & 15;
        int r2 = r + half; if (r2 > 63) r2 = 63;  // replicated tail, never read
        uint2 a  = *reinterpret_cast<const uint2*>(&pa[r  * 64 + c4 * 4]);
        uint2 bq = *reinterpret_cast<const uint2*>(&pa[r2 * 64 + c4 * 4]);
        uint2 m; m.x = bfmax2(a.x, bq.x); m.y = bfmax2(a.y, bq.y);
        *reinterpret_cast<uint2*>(&pb[r * 64 + c4 * 4]) = m;
        *reinterpret_cast<uint2*>(dst_g + r * H_ + c4 * 4) = m;
      }
      u16* tmp = pa; pa = pb; pb = tmp;
    }
  } else {
    int gb = bid - 256;   // 0..31
    if (gb == 0) {
      for (int n = tid; n < NWIN; n += 256) {
        int w = 2, rem = n;
        while (rem >= 65 - w) { rem -= 65 - w; ++w; }
        int s = rem;
        int k = 31 - __clz(w);
        int e2 = s + w - (1 << k);
        widx[n] = (u16)(s | (e2 << 6) | (k << 12));
      }
    }
    for (int q = tid; q < 2048; q += 256) {
      int idx = gb * 2048 + q;
      int e = idx & 7, L = (idx >> 3) & 63, j = (idx >> 9) & 7;
      int k2i = (idx >> 12) & 1, kc = idx >> 13;
      int n  = j * 16 + (L & 15);
      int kq = kc * 64 + k2i * 32 + (L >> 4) * 8 + e;
      w1tf[idx] = f2bf(W1[kq * ATT_ + n]);
    }
  }
}

// ====== k2: pooled @ W1 (MFMA bf16) + bias + relu + @W2 -> scores ==========
// grid (32, 32), 256 thr. Tile: 64 windows x 128 att, K=512 in 8 chunks of 64.
// Wave grid 4x1 in M. A: R11 slab staging (coalesced global -> swizzled LDS,
// register prefetch-1; 64-window tile spans <=2 adjacent levels). B: frag-
// major w1tf chunk staged CONTIGUOUSLY into Bs (16 KB memcpy per chunk);
// B-frag read = ds_read_b128 of 1024 consecutive bytes per wave (conflict-
// free, zero swizzle arithmetic).
__launch_bounds__(256)
__attribute__((amdgpu_waves_per_eu(1, 4)))
__global__ void k2_scores(const u16* __restrict__ table, const u16* __restrict__ w1tf,
                          const float* __restrict__ b1, const float* __restrict__ w2,
                          const u16* __restrict__ widx, float* __restrict__ scores) {
  const int b = blockIdx.y, mt = blockIdx.x;
  __shared__ u16 Ts[128 * 64];   // two level slabs, swizzled, 16 KB
  __shared__ u16 Bs[8192];       // frag-major W1 chunk, contiguous, 16 KB
  __shared__ u16 widx_l[64];
  __shared__ float b1s[128], w2s[128];
  int tid = threadIdx.x;
  if (tid < 64) {
    int n = mt * 64 + tid; if (n > NWIN - 1) n = NWIN - 1;  // pad-clamp
    widx_l[tid] = widx[n];
  }
  if (tid < 128) { b1s[tid] = b1[tid]; w2s[tid] = w2[tid]; }
  __syncthreads();

  const int lv_lo = widx_l[0] >> 12;   // tile's lowest level (>=1); max lv_lo+1
  const u16* tb = table + (size_t)b * TLEV * S_ * H_ + (size_t)(lv_lo - 1) * S_ * H_;

  // Ts staging slots (1024 tasks / 256 thr = 4): t = tid + i*256,
  // row = t>>3 in 0..127, c = t&7; swizzled dst = row*64 + ((c^(row&7))*8)
  int t0 = tid, t1 = tid + 256, t2 = tid + 512, t3 = tid + 768;
  int r0 = t0 >> 3, r1 = t1 >> 3, r2 = t2 >> 3, r3 = t3 >> 3;
  int c0 = t0 & 7,  c1 = t1 & 7,  c2 = t2 & 7,  c3 = t3 & 7;
  const u16* ts0 = tb + r0 * H_ + c0 * 8;
  const u16* ts1 = tb + r1 * H_ + c1 * 8;
  const u16* ts2 = tb + r2 * H_ + c2 * 8;
  const u16* ts3 = tb + r3 * H_ + c3 * 8;
  int sd0 = r0 * 64 + ((c0 ^ (r0 & 7)) * 8);
  int sd1 = r1 * 64 + ((c1 ^ (r1 & 7)) * 8);
  int sd2 = r2 * 64 + ((c2 ^ (r2 & 7)) * 8);
  int sd3 = r3 * 64 + ((c3 ^ (r3 & 7)) * 8);
  // Bs staging: 4 contiguous 16B copies per thread; slot i at u16 offset
  // tid*8 + i*2048 (both src-within-chunk and LDS dst).
  int bo0 = tid * 8, bo1 = bo0 + 2048, bo2 = bo0 + 4096, bo3 = bo0 + 6144;

  int wid = tid >> 6, lane = tid & 63;
  int lrow = lane & 15, quad = lane >> 4;

  // A-fragment addresses: this wave's window m = wid*16 + lrow; {s,e2} x k2i
  int aoff[2][2];
  {
    int pk = widx_l[wid * 16 + lrow];
    int s = pk & 63, e2 = (pk >> 6) & 63, lv = (pk >> 12) - lv_lo;  // 0 or 1
    int rs = lv * 64 + s, re = lv * 64 + e2;
#pragma unroll
    for (int k2i = 0; k2i < 2; ++k2i) {
      int c = quad + k2i * 4;
      aoff[k2i][0] = rs * 64 + ((c ^ (rs & 7)) * 8);
      aoff[k2i][1] = re * 64 + ((c ^ (re & 7)) * 8);
    }
  }

  uint4 rT0, rT1, rT2, rT3, rB0, rB1, rB2, rB3;

#define ISSUE(KC) do { \
  int kk_ = (KC) * 64; \
  const u16* wsrc_ = w1tf + (KC) * 8192; \
  rT0 = *reinterpret_cast<const uint4*>(ts0 + kk_); \
  rT1 = *reinterpret_cast<const uint4*>(ts1 + kk_); \
  rT2 = *reinterpret_cast<const uint4*>(ts2 + kk_); \
  rT3 = *reinterpret_cast<const uint4*>(ts3 + kk_); \
  rB0 = *reinterpret_cast<const uint4*>(wsrc_ + bo0); \
  rB1 = *reinterpret_cast<const uint4*>(wsrc_ + bo1); \
  rB2 = *reinterpret_cast<const uint4*>(wsrc_ + bo2); \
  rB3 = *reinterpret_cast<const uint4*>(wsrc_ + bo3); \
} while (0)

#define STAGE() do { \
  *reinterpret_cast<uint4*>(&Ts[sd0]) = rT0; \
  *reinterpret_cast<uint4*>(&Ts[sd1]) = rT1; \
  *reinterpret_cast<uint4*>(&Ts[sd2]) = rT2; \
  *reinterpret_cast<uint4*>(&Ts[sd3]) = rT3; \
  *reinterpret_cast<uint4*>(&Bs[bo0]) = rB0; \
  *reinterpret_cast<uint4*>(&Bs[bo1]) = rB1; \
  *reinterpret_cast<uint4*>(&Bs[bo2]) = rB2; \
  *reinterpret_cast<uint4*>(&Bs[bo3]) = rB3; \
} while (0)

  ISSUE(0);

  f32x4 acc[8];
#pragma unroll
  for (int j = 0; j < 8; ++j) acc[j] = (f32x4){0.f, 0.f, 0.f, 0.f};

  for (int kc = 0; kc < 8; ++kc) {
    __syncthreads();   // previous chunk's fragment reads complete
    STAGE();
    __syncthreads();
    if (kc < 7) ISSUE(kc + 1);   // hides under the MFMA chunk below
#pragma unroll
    for (int k2i = 0; k2i < 2; ++k2i) {
      uint4 va = *reinterpret_cast<const uint4*>(&Ts[aoff[k2i][0]]);
      uint4 vb = *reinterpret_cast<const uint4*>(&Ts[aoff[k2i][1]]);
      bf16x8 af = as_bf16x8(bfmax8(va, vb));
      const u16* bk = &Bs[k2i * 4096 + lane * 8];
#pragma unroll
      for (int j = 0; j < 8; ++j) {
        bf16x8 bfr = *reinterpret_cast<const bf16x8*>(bk + j * 512);
        acc[j] = __builtin_amdgcn_mfma_f32_16x16x32_bf16(af, bfr, acc[j], 0, 0, 0);
      }
    }
  }

#undef ISSUE
#undef STAGE

  // epilogue: score[m] = sum_n relu(hid+b1)*w2 (b2 dropped: softmax-invariant)
  // C layout: row = quad*4 + r, col = lrow. Reduce over 128 cols = 8 j-frags
  // in-register + 16-lane shfl; lane lrow==0 stores row quad*4+r directly.
#pragma unroll
  for (int r = 0; r < 4; ++r) {
    float p = 0.f;
#pragma unroll
    for (int j = 0; j < 8; ++j) {
      int n = j * 16 + lrow;
      float v = acc[j][r] + b1s[n];
      p += (v > 0.f ? v : 0.f) * w2s[n];
    }
    p += __shfl_xor(p, 1, 16);
    p += __shfl_xor(p, 2, 16);
    p += __shfl_xor(p, 4, 16);
    p += __shfl_xor(p, 8, 16);
    if (lrow == 0) {
      int nw = mt * 64 + wid * 16 + quad * 4 + r;
      if (nw < NWIN) scores[b * NWIN + nw] = p;
    }
  }
}

// ========= k34: per-block softmax (redundant) + attn-weighted sum ==========
// grid (32, 32), 256 thr; 16-wide h slice per block (R14: halves the
// dominant per-thread window loop vs the 32-wide version). Softmax
// recomputed per block; 1/sum folded into the final store.
__launch_bounds__(256)
__global__ void k34_out(const u16* __restrict__ table, const float* __restrict__ scores,
                        const u16* __restrict__ widx, float* __restrict__ out) {
  int hc = blockIdx.x, b = blockIdx.y, tid = threadIdx.x;
  __shared__ u16 Tl[6 * 64 * 16];       // 6 KB: levels 1..6, 16-col slice
  __shared__ float attn_l[NWIN];        // 8 KB, unnormalized exp
  __shared__ u16 widx_l[NWIN];          // 4 KB
  __shared__ float red[16][16];
  __shared__ float wredM[4], wredS[4];
  const u16* tb = table + (size_t)b * TLEV * S_ * H_;   // levels 1..6
  int h0 = hc * 16;
  int lane = tid & 63, wid = tid >> 6;

  for (int t = tid; t < 6 * 64 * 2; t += 256) {   // 768 tasks x 16 B
    int row = t >> 1, c = t & 1;
    uint4 v = *reinterpret_cast<const uint4*>(tb + row * H_ + h0 + c * 8);
    *reinterpret_cast<uint4*>(&Tl[row * 16 + c * 8]) = v;
  }
  for (int n = tid; n < NWIN; n += 256) widx_l[n] = widx[n];

  float mx = -1e30f;
  for (int n = tid; n < NWIN; n += 256) {
    float v = scores[b * NWIN + n];
    attn_l[n] = v;
    mx = fmaxf(mx, v);
  }
#pragma unroll
  for (int off = 32; off > 0; off >>= 1) mx = fmaxf(mx, __shfl_xor(mx, off, 64));
  if (lane == 0) wredM[wid] = mx;
  __syncthreads();   // also covers the Tl / widx_l / attn_l staging above
  mx = fmaxf(fmaxf(wredM[0], wredM[1]), fmaxf(wredM[2], wredM[3]));
  float sum = 0.f;
  for (int n = tid; n < NWIN; n += 256) {
    float e = __expf(attn_l[n] - mx);
    attn_l[n] = e;
    sum += e;
  }
#pragma unroll
  for (int off = 32; off > 0; off >>= 1) sum += __shfl_xor(sum, off, 64);
  if (lane == 0) wredS[wid] = sum;
  __syncthreads();
  float inv = 1.f / (wredS[0] + wredS[1] + wredS[2] + wredS[3]);

  int h = tid & 15, g = tid >> 4;   // 16 groups x 126 windows each
  float acc = 0.f;
  for (int n = g * 126; n < g * 126 + 126; ++n) {
    int pk = widx_l[n];
    int s = pk & 63, e2 = (pk >> 6) & 63, lv = pk >> 12;
    float va = bf2f(Tl[((lv - 1) * 64 + s) * 16 + h]);
    float vb = bf2f(Tl[((lv - 1) * 64 + e2) * 16 + h]);
    acc += attn_l[n] * fmaxf(va, vb);
  }
  red[g][h] = acc;
  __syncthreads();
  if (tid < 16) {
    float s2 = 0.f;
#pragma unroll
    for (int g2 = 0; g2 < 16; ++g2) s2 += red[g2][tid];
    out[b * H_ + h0 + tid] = s2 * inv;
  }
}

// ================================ launch ===================================
extern "C" void kernel_launch(void* const* d_in, const int* in_sizes, int n_in,
                              void* d_out, int out_size, void* d_ws, size_t ws_size,
                              hipStream_t stream) {
  const float* lstm = (const float*)d_in[0];
  const float* W1   = (const float*)d_in[1];
  const float* b1   = (const float*)d_in[2];
  const float* W2   = (const float*)d_in[3];
  // d_in[4] = b2: uniform shift ahead of softmax -> no output effect, unused.
  float* out = (float*)d_out;

  char* ws = (char*)d_ws;
  // ws layout: widx u16 [0,4096) | w1tf bf16 [4096,135168)
  //            | table bf16 levels 1..6 (12.58 MB) | scores f32 (258048 B)
  u16*   widx   = (u16*)(ws + 0);
  u16*   w1tf   = (u16*)(ws + 4096);
  u16*   table  = (u16*)(ws + 135168);
  float* scores = (float*)(ws + 12718080);

  k01_init <<<288, 256, 0, stream>>>(lstm, W1, table, w1tf, widx);
  k2_scores<<<dim3(32, B_), 256, 0, stream>>>(table, w1tf, b1, W2, widx, scores);
  k34_out  <<<dim3(32, B_), 256, 0, stream>>>(table, scores, widx, out);
}

// Round 15
// 117.293 us; speedup vs baseline: 1.4433x; 1.0066x over previous
//
#include <hip/hip_runtime.h>
#include <stdint.h>

// R15: k2 re-tiled to 128 windows x 128 att per block, 512 thr (8 waves,
// grid 16x32 = 2 blocks/CU, 16 waves/CU unchanged). Wave = 32 win x 64 att:
// B-frags reused across 2 M-frags -> LDS ops/wave/chunk 28 -> 20 (B reads
// halve per window), B global re-staging per batch halves. Same verified
// 16x16x32 fragment layouts, swizzled Ts, frag-major contiguous Bs.
// Aligned 128-window tiles span <=2 adjacent levels (boundaries at
// 125/363/791/1455/2015: each tile crosses at most one).

typedef unsigned short u16;
typedef unsigned int u32;

#define B_    32
#define S_    64
#define H_    512
#define ATT_  128
#define NWIN  2016
#define NLEV  7
#define TLEV  6   // stored levels: 1..6

typedef __bf16 bf16x8 __attribute__((ext_vector_type(8)));
typedef float  f32x4  __attribute__((ext_vector_type(4)));

__device__ __forceinline__ float asf(u32 i) {
  union { u32 i; float f; } v; v.i = i; return v.f;
}
__device__ __forceinline__ u32 asu(float f) {
  union { float f; u32 i; } v; v.f = f; return v.i;
}
__device__ __forceinline__ float bf2f(u16 u) { return asf(((u32)u) << 16); }
__device__ __forceinline__ u16 f2bf(float f) {
  u32 i = asu(f);
  i += 0x7fffu + ((i >> 16) & 1u);   // round-to-nearest-even
  return (u16)(i >> 16);
}
// Exact bf16x2 max: halves viewed as f32 (low mantissa zero) -> v_max_f32
// exact; repack high halves. bf16 rounding is monotone, so the bf16 sparse
// table introduces no extra error vs rounding the pooled values.
__device__ __forceinline__ u32 bfmax2(u32 a, u32 b) {
  float a0 = asf(a << 16), a1 = asf(a & 0xffff0000u);
  float b0 = asf(b << 16), b1 = asf(b & 0xffff0000u);
  u32 m0 = asu(fmaxf(a0, b0)), m1 = asu(fmaxf(a1, b1));
  return (m1 & 0xffff0000u) | (m0 >> 16);
}
__device__ __forceinline__ uint4 bfmax8(uint4 a, uint4 b) {
  uint4 m;
  m.x = bfmax2(a.x, b.x); m.y = bfmax2(a.y, b.y);
  m.z = bfmax2(a.z, b.z); m.w = bfmax2(a.w, b.w);
  return m;
}
__device__ __forceinline__ bf16x8 as_bf16x8(uint4 v) {
  union { uint4 u; bf16x8 h; } c; c.u = v; return c.h;
}

// ============ k01: sparse table build + widx + W1 frag-major (one launch) ===
// blocks [0,256): per-(hc,b) 64-column slab; level 0 stays in LDS only,
// levels 1..6 stream to global (level L at offset (L-1)*S*H).
// blocks [256,288): w1tf fragment-major emit; block 256 additionally emits
// widx. w1tf flat index idx: e=idx&7, L=(idx>>3)&63, j=(idx>>9)&7,
// k2i=(idx>>12)&1, kc=idx>>13; value = W1[kq*128+n], n=j*16+(L&15),
// kq = kc*64 + k2i*32 + (L>>4)*8 + e. Chunk kc = 16 KB at idx [kc*8192,+8192).
__launch_bounds__(256)
__global__ void k01_init(const float* __restrict__ lstm, const float* __restrict__ W1,
                         u16* __restrict__ table, u16* __restrict__ w1tf,
                         u16* __restrict__ widx) {
  int bid = blockIdx.x, tid = threadIdx.x;
  __shared__ u16 bufA[64 * 64], bufB[64 * 64];
  if (bid < 256) {
    int hc = bid & 7, b = bid >> 3;
    const float* src = lstm + (size_t)b * S_ * H_ + hc * 64;
    u16* tb = table + (size_t)b * TLEV * S_ * H_ + hc * 64;
    // level 0: fp32 -> bf16 into LDS only (never read from global)
    for (int t = tid; t < 64 * 16; t += 256) {
      int r = t >> 4, c4 = t & 15;
      float4 f = *reinterpret_cast<const float4*>(src + r * H_ + c4 * 4);
      ushort4 u;
      u.x = f2bf(f.x); u.y = f2bf(f.y); u.z = f2bf(f.z); u.w = f2bf(f.w);
      *reinterpret_cast<ushort4*>(&bufA[r * 64 + c4 * 4]) = u;
    }
    u16* pa = bufA; u16* pb = bufB;
    for (int k = 1; k < NLEV; ++k) {
      __syncthreads();
      int half = 1 << (k - 1);
      u16* dst_g = tb + (size_t)(k - 1) * S_ * H_;
      for (int t = tid; t < 64 * 16; t += 256) {
        int r = t >> 4, c4 = t & 15;
        int r2 = r + half; if (r2 > 63) r2 = 63;  // replicated tail, never read
        uint2 a  = *reinterpret_cast<const uint2*>(&pa[r  * 64 + c4 * 4]);
        uint2 bq = *reinterpret_cast<const uint2*>(&pa[r2 * 64 + c4 * 4]);
        uint2 m; m.x = bfmax2(a.x, bq.x); m.y = bfmax2(a.y, bq.y);
        *reinterpret_cast<uint2*>(&pb[r * 64 + c4 * 4]) = m;
        *reinterpret_cast<uint2*>(dst_g + r * H_ + c4 * 4) = m;
      }
      u16* tmp = pa; pa = pb; pb = tmp;
    }
  } else {
    int gb = bid - 256;   // 0..31
    if (gb == 0) {
      for (int n = tid; n < NWIN; n += 256) {
        int w = 2, rem = n;
        while (rem >= 65 - w) { rem -= 65 - w; ++w; }
        int s = rem;
        int k = 31 - __clz(w);
        int e2 = s + w - (1 << k);
        widx[n] = (u16)(s | (e2 << 6) | (k << 12));
      }
    }
    for (int q = tid; q < 2048; q += 256) {
      int idx = gb * 2048 + q;
      int e = idx & 7, L = (idx >> 3) & 63, j = (idx >> 9) & 7;
      int k2i = (idx >> 12) & 1, kc = idx >> 13;
      int n  = j * 16 + (L & 15);
      int kq = kc * 64 + k2i * 32 + (L >> 4) * 8 + e;
      w1tf[idx] = f2bf(W1[kq * ATT_ + n]);
    }
  }
}

// ====== k2: pooled @ W1 (MFMA bf16) + bias + relu + @W2 -> scores ==========
// grid (16, 32), 512 thr. Tile: 128 windows x 128 att, K=512 in 8 chunks.
// Wave grid 4M x 2N: wave (wm,wn) owns windows [wm*32, wm*32+32) x att
// [wn*64, wn*64+64) -> 2 A-frags (reused over 4 B-frags) per k2i.
// A: swizzled 2-level slab staging with register prefetch-1. B: frag-major
// w1tf chunk staged contiguously; frag read = contiguous ds_read_b128.
__launch_bounds__(512)
__attribute__((amdgpu_waves_per_eu(1, 4)))
__global__ void k2_scores(const u16* __restrict__ table, const u16* __restrict__ w1tf,
                          const float* __restrict__ b1, const float* __restrict__ w2,
                          const u16* __restrict__ widx, float* __restrict__ scores) {
  const int b = blockIdx.y, mt = blockIdx.x;
  __shared__ u16 Ts[128 * 64];     // two level slabs, swizzled, 16 KB
  __shared__ u16 Bs[8192];         // frag-major W1 chunk, contiguous, 16 KB
  __shared__ u16 widx_l[128];
  __shared__ float b1s[128], w2s[128];
  __shared__ float sc2[2][128];    // per-N-half partial scores
  int tid = threadIdx.x;
  if (tid < 128) {
    int n = mt * 128 + tid; if (n > NWIN - 1) n = NWIN - 1;  // pad-clamp
    widx_l[tid] = widx[n];
    b1s[tid] = b1[tid]; w2s[tid] = w2[tid];
  }
  __syncthreads();

  const int lv_lo = widx_l[0] >> 12;   // tile's lowest level (>=1); max lv_lo+1
  const u16* tb = table + (size_t)b * TLEV * S_ * H_ + (size_t)(lv_lo - 1) * S_ * H_;

  // Ts staging slots (1024 tasks / 512 thr = 2): t = tid, tid+512;
  // row = t>>3 in 0..127, c = t&7; swizzled dst = row*64 + ((c^(row&7))*8)
  int t0 = tid, t1 = tid + 512;
  int r0 = t0 >> 3, r1 = t1 >> 3;
  int c0 = t0 & 7,  c1 = t1 & 7;
  const u16* ts0 = tb + r0 * H_ + c0 * 8;
  const u16* ts1 = tb + r1 * H_ + c1 * 8;
  int sd0 = r0 * 64 + ((c0 ^ (r0 & 7)) * 8);
  int sd1 = r1 * 64 + ((c1 ^ (r1 & 7)) * 8);
  // Bs staging: 2 contiguous 16B copies per thread at u16 offsets
  // tid*8 and tid*8 + 4096 (same offset in chunk source and LDS dst).
  int bo0 = tid * 8, bo1 = bo0 + 4096;

  int wid = tid >> 6, lane = tid & 63;
  int wm = wid & 3, wn = wid >> 2;
  int lrow = lane & 15, quad = lane >> 4;

  // A-fragment addresses: windows m = wm*32 + mi*16 + lrow; {s,e2} x k2i
  int aoff[2][2][2];
#pragma unroll
  for (int mi = 0; mi < 2; ++mi) {
    int pk = widx_l[wm * 32 + mi * 16 + lrow];
    int s = pk & 63, e2 = (pk >> 6) & 63, lv = (pk >> 12) - lv_lo;  // 0 or 1
    int rs = lv * 64 + s, re = lv * 64 + e2;
#pragma unroll
    for (int k2i = 0; k2i < 2; ++k2i) {
      int c = quad + k2i * 4;
      aoff[mi][k2i][0] = rs * 64 + ((c ^ (rs & 7)) * 8);
      aoff[mi][k2i][1] = re * 64 + ((c ^ (re & 7)) * 8);
    }
  }

  uint4 rT0, rT1, rB0, rB1;

#define ISSUE(KC) do { \
  int kk_ = (KC) * 64; \
  const u16* wsrc_ = w1tf + (KC) * 8192; \
  rT0 = *reinterpret_cast<const uint4*>(ts0 + kk_); \
  rT1 = *reinterpret_cast<const uint4*>(ts1 + kk_); \
  rB0 = *reinterpret_cast<const uint4*>(wsrc_ + bo0); \
  rB1 = *reinterpret_cast<const uint4*>(wsrc_ + bo1); \
} while (0)

#define STAGE() do { \
  *reinterpret_cast<uint4*>(&Ts[sd0]) = rT0; \
  *reinterpret_cast<uint4*>(&Ts[sd1]) = rT1; \
  *reinterpret_cast<uint4*>(&Bs[bo0]) = rB0; \
  *reinterpret_cast<uint4*>(&Bs[bo1]) = rB1; \
} while (0)

  ISSUE(0);

  f32x4 acc[2][4];
#pragma unroll
  for (int mi = 0; mi < 2; ++mi)
#pragma unroll
    for (int j = 0; j < 4; ++j) acc[mi][j] = (f32x4){0.f, 0.f, 0.f, 0.f};

  for (int kc = 0; kc < 8; ++kc) {
    __syncthreads();   // previous chunk's fragment reads complete
    STAGE();
    __syncthreads();
    if (kc < 7) ISSUE(kc + 1);   // hides under the MFMA chunk below
#pragma unroll
    for (int k2i = 0; k2i < 2; ++k2i) {
      bf16x8 af[2];
#pragma unroll
      for (int mi = 0; mi < 2; ++mi) {
        uint4 va = *reinterpret_cast<const uint4*>(&Ts[aoff[mi][k2i][0]]);
        uint4 vb = *reinterpret_cast<const uint4*>(&Ts[aoff[mi][k2i][1]]);
        af[mi] = as_bf16x8(bfmax8(va, vb));
      }
      const u16* bk = &Bs[(k2i * 8 + wn * 4) * 512 + lane * 8];
#pragma unroll
      for (int j = 0; j < 4; ++j) {
        bf16x8 bfr = *reinterpret_cast<const bf16x8*>(bk + j * 512);
        acc[0][j] = __builtin_amdgcn_mfma_f32_16x16x32_bf16(af[0], bfr, acc[0][j], 0, 0, 0);
        acc[1][j] = __builtin_amdgcn_mfma_f32_16x16x32_bf16(af[1], bfr, acc[1][j], 0, 0, 0);
      }
    }
  }

#undef ISSUE
#undef STAGE

  // epilogue: score[m] = sum_n relu(hid+b1)*w2 (b2 dropped: softmax-invariant)
  // C layout: row = quad*4 + r, col = lrow (col n = wn*64 + j*16 + lrow).
  // Per-wave partial over its 64-att half -> sc2[wn][row]; combine after sync.
#pragma unroll
  for (int mi = 0; mi < 2; ++mi) {
#pragma unroll
    for (int r = 0; r < 4; ++r) {
      float p = 0.f;
#pragma unroll
      for (int j = 0; j < 4; ++j) {
        int n = wn * 64 + j * 16 + lrow;
        float v = acc[mi][j][r] + b1s[n];
        p += (v > 0.f ? v : 0.f) * w2s[n];
      }
      p += __shfl_xor(p, 1, 16);
      p += __shfl_xor(p, 2, 16);
      p += __shfl_xor(p, 4, 16);
      p += __shfl_xor(p, 8, 16);
      if (lrow == 0) sc2[wn][wm * 32 + mi * 16 + quad * 4 + r] = p;
    }
  }
  __syncthreads();
  if (tid < 128) {
    int nw = mt * 128 + tid;
    if (nw < NWIN) scores[b * NWIN + nw] = sc2[0][tid] + sc2[1][tid];
  }
}

// ========= k34: per-block softmax (redundant) + attn-weighted sum ==========
// grid (32, 32), 256 thr; 16-wide h slice per block. Softmax recomputed per
// block; 1/sum folded into the final store. Table holds levels 1..6.
__launch_bounds__(256)
__global__ void k34_out(const u16* __restrict__ table, const float* __restrict__ scores,
                        const u16* __restrict__ widx, float* __restrict__ out) {
  int hc = blockIdx.x, b = blockIdx.y, tid = threadIdx.x;
  __shared__ u16 Tl[6 * 64 * 16];       // 6 KB: levels 1..6, 16-col slice
  __shared__ float attn_l[NWIN];        // 8 KB, unnormalized exp
  __shared__ u16 widx_l[NWIN];          // 4 KB
  __shared__ float red[16][16];
  __shared__ float wredM[4], wredS[4];
  const u16* tb = table + (size_t)b * TLEV * S_ * H_;   // levels 1..6
  int h0 = hc * 16;
  int lane = tid & 63, wid = tid >> 6;

  for (int t = tid; t < 6 * 64 * 2; t += 256) {   // 768 tasks x 16 B
    int row = t >> 1, c = t & 1;
    uint4 v = *reinterpret_cast<const uint4*>(tb + row * H_ + h0 + c * 8);
    *reinterpret_cast<uint4*>(&Tl[row * 16 + c * 8]) = v;
  }
  for (int n = tid; n < NWIN; n += 256) widx_l[n] = widx[n];

  float mx = -1e30f;
  for (int n = tid; n < NWIN; n += 256) {
    float v = scores[b * NWIN + n];
    attn_l[n] = v;
    mx = fmaxf(mx, v);
  }
#pragma unroll
  for (int off = 32; off > 0; off >>= 1) mx = fmaxf(mx, __shfl_xor(mx, off, 64));
  if (lane == 0) wredM[wid] = mx;
  __syncthreads();   // also covers the Tl / widx_l / attn_l staging above
  mx = fmaxf(fmaxf(wredM[0], wredM[1]), fmaxf(wredM[2], wredM[3]));
  float sum = 0.f;
  for (int n = tid; n < NWIN; n += 256) {
    float e = __expf(attn_l[n] - mx);
    attn_l[n] = e;
    sum += e;
  }
#pragma unroll
  for (int off = 32; off > 0; off >>= 1) sum += __shfl_xor(sum, off, 64);
  if (lane == 0) wredS[wid] = sum;
  __syncthreads();
  float inv = 1.f / (wredS[0] + wredS[1] + wredS[2] + wredS[3]);

  int h = tid & 15, g = tid >> 4;   // 16 groups x 126 windows each
  float acc = 0.f;
  for (int n = g * 126; n < g * 126 + 126; ++n) {
    int pk = widx_l[n];
    int s = pk & 63, e2 = (pk >> 6) & 63, lv = pk >> 12;
    float va = bf2f(Tl[((lv - 1) * 64 + s) * 16 + h]);
    float vb = bf2f(Tl[((lv - 1) * 64 + e2) * 16 + h]);
    acc += attn_l[n] * fmaxf(va, vb);
  }
  red[g][h] = acc;
  __syncthreads();
  if (tid < 16) {
    float s2 = 0.f;
#pragma unroll
    for (int g2 = 0; g2 < 16; ++g2) s2 += red[g2][tid];
    out[b * H_ + h0 + tid] = s2 * inv;
  }
}

// ================================ launch ===================================
extern "C" void kernel_launch(void* const* d_in, const int* in_sizes, int n_in,
                              void* d_out, int out_size, void* d_ws, size_t ws_size,
                              hipStream_t stream) {
  const float* lstm = (const float*)d_in[0];
  const float* W1   = (const float*)d_in[1];
  const float* b1   = (const float*)d_in[2];
  const float* W2   = (const float*)d_in[3];
  // d_in[4] = b2: uniform shift ahead of softmax -> no output effect, unused.
  float* out = (float*)d_out;

  char* ws = (char*)d_ws;
  // ws layout: widx u16 [0,4096) | w1tf bf16 [4096,135168)
  //            | table bf16 levels 1..6 (12.58 MB) | scores f32 (258048 B)
  u16*   widx   = (u16*)(ws + 0);
  u16*   w1tf   = (u16*)(ws + 4096);
  u16*   table  = (u16*)(ws + 135168);
  float* scores = (float*)(ws + 12718080);

  k01_init <<<288, 256, 0, stream>>>(lstm, W1, table, w1tf, widx);
  k2_scores<<<dim3(16, B_), 512, 0, stream>>>(table, w1tf, b1, W2, widx, scores);
  k34_out  <<<dim3(32, B_), 256, 0, stream>>>(table, scores, widx, out);
}

// Round 16
// 116.882 us; speedup vs baseline: 1.4484x; 1.0035x over previous
//
#include <hip/hip_runtime.h>
#include <stdint.h>

// R16 = R15 + XCD-aware block swizzle (single-variable experiment).
// Theory: k2's residual cost is A-staging latency — the 12.6 MB table
// thrashes every XCD's 4 MB L2 under round-robin dispatch. Swizzle maps
// same-XCD blocks (bid%8 under round-robin) to only 4 batches, shrinking
// the per-XCD working set to 1.7 MB (fits L2). Applied to k2 and k34.

typedef unsigned short u16;
typedef unsigned int u32;

#define B_    32
#define S_    64
#define H_    512
#define ATT_  128
#define NWIN  2016
#define NLEV  7
#define TLEV  6   // stored levels: 1..6

typedef __bf16 bf16x8 __attribute__((ext_vector_type(8)));
typedef float  f32x4  __attribute__((ext_vector_type(4)));

__device__ __forceinline__ float asf(u32 i) {
  union { u32 i; float f; } v; v.i = i; return v.f;
}
__device__ __forceinline__ u32 asu(float f) {
  union { float f; u32 i; } v; v.f = f; return v.i;
}
__device__ __forceinline__ float bf2f(u16 u) { return asf(((u32)u) << 16); }
__device__ __forceinline__ u16 f2bf(float f) {
  u32 i = asu(f);
  i += 0x7fffu + ((i >> 16) & 1u);   // round-to-nearest-even
  return (u16)(i >> 16);
}
// Exact bf16x2 max: halves viewed as f32 (low mantissa zero) -> v_max_f32
// exact; repack high halves. bf16 rounding is monotone, so the bf16 sparse
// table introduces no extra error vs rounding the pooled values.
__device__ __forceinline__ u32 bfmax2(u32 a, u32 b) {
  float a0 = asf(a << 16), a1 = asf(a & 0xffff0000u);
  float b0 = asf(b << 16), b1 = asf(b & 0xffff0000u);
  u32 m0 = asu(fmaxf(a0, b0)), m1 = asu(fmaxf(a1, b1));
  return (m1 & 0xffff0000u) | (m0 >> 16);
}
__device__ __forceinline__ uint4 bfmax8(uint4 a, uint4 b) {
  uint4 m;
  m.x = bfmax2(a.x, b.x); m.y = bfmax2(a.y, b.y);
  m.z = bfmax2(a.z, b.z); m.w = bfmax2(a.w, b.w);
  return m;
}
__device__ __forceinline__ bf16x8 as_bf16x8(uint4 v) {
  union { uint4 u; bf16x8 h; } c; c.u = v; return c.h;
}

// ============ k01: sparse table build + widx + W1 frag-major (one launch) ===
// blocks [0,256): per-(hc,b) 64-column slab; level 0 stays in LDS only,
// levels 1..6 stream to global (level L at offset (L-1)*S*H).
// blocks [256,288): w1tf fragment-major emit; block 256 additionally emits
// widx. w1tf flat index idx: e=idx&7, L=(idx>>3)&63, j=(idx>>9)&7,
// k2i=(idx>>12)&1, kc=idx>>13; value = W1[kq*128+n], n=j*16+(L&15),
// kq = kc*64 + k2i*32 + (L>>4)*8 + e. Chunk kc = 16 KB at idx [kc*8192,+8192).
__launch_bounds__(256)
__global__ void k01_init(const float* __restrict__ lstm, const float* __restrict__ W1,
                         u16* __restrict__ table, u16* __restrict__ w1tf,
                         u16* __restrict__ widx) {
  int bid = blockIdx.x, tid = threadIdx.x;
  __shared__ u16 bufA[64 * 64], bufB[64 * 64];
  if (bid < 256) {
    int hc = bid & 7, b = bid >> 3;
    const float* src = lstm + (size_t)b * S_ * H_ + hc * 64;
    u16* tb = table + (size_t)b * TLEV * S_ * H_ + hc * 64;
    // level 0: fp32 -> bf16 into LDS only (never read from global)
    for (int t = tid; t < 64 * 16; t += 256) {
      int r = t >> 4, c4 = t & 15;
      float4 f = *reinterpret_cast<const float4*>(src + r * H_ + c4 * 4);
      ushort4 u;
      u.x = f2bf(f.x); u.y = f2bf(f.y); u.z = f2bf(f.z); u.w = f2bf(f.w);
      *reinterpret_cast<ushort4*>(&bufA[r * 64 + c4 * 4]) = u;
    }
    u16* pa = bufA; u16* pb = bufB;
    for (int k = 1; k < NLEV; ++k) {
      __syncthreads();
      int half = 1 << (k - 1);
      u16* dst_g = tb + (size_t)(k - 1) * S_ * H_;
      for (int t = tid; t < 64 * 16; t += 256) {
        int r = t >> 4, c4 = t & 15;
        int r2 = r + half; if (r2 > 63) r2 = 63;  // replicated tail, never read
        uint2 a  = *reinterpret_cast<const uint2*>(&pa[r  * 64 + c4 * 4]);
        uint2 bq = *reinterpret_cast<const uint2*>(&pa[r2 * 64 + c4 * 4]);
        uint2 m; m.x = bfmax2(a.x, bq.x); m.y = bfmax2(a.y, bq.y);
        *reinterpret_cast<uint2*>(&pb[r * 64 + c4 * 4]) = m;
        *reinterpret_cast<uint2*>(dst_g + r * H_ + c4 * 4) = m;
      }
      u16* tmp = pa; pa = pb; pb = tmp;
    }
  } else {
    int gb = bid - 256;   // 0..31
    if (gb == 0) {
      for (int n = tid; n < NWIN; n += 256) {
        int w = 2, rem = n;
        while (rem >= 65 - w) { rem -= 65 - w; ++w; }
        int s = rem;
        int k = 31 - __clz(w);
        int e2 = s + w - (1 << k);
        widx[n] = (u16)(s | (e2 << 6) | (k << 12));
      }
    }
    for (int q = tid; q < 2048; q += 256) {
      int idx = gb * 2048 + q;
      int e = idx & 7, L = (idx >> 3) & 63, j = (idx >> 9) & 7;
      int k2i = (idx >> 12) & 1, kc = idx >> 13;
      int n  = j * 16 + (L & 15);
      int kq = kc * 64 + k2i * 32 + (L >> 4) * 8 + e;
      w1tf[idx] = f2bf(W1[kq * ATT_ + n]);
    }
  }
}

// ====== k2: pooled @ W1 (MFMA bf16) + bias + relu + @W2 -> scores ==========
// grid 512 (1D, XCD-swizzled), 512 thr. Tile: 128 windows x 128 att, K=512
// in 8 chunks. Block mapping: xcd = bid&7, q = bid>>3; b = xcd*4 + (q&3),
// mt = q>>2 — same-XCD blocks serve only 4 batches (1.7 MB working set,
// fits 4 MB L2). Wave grid 4M x 2N. A: swizzled 2-level slab staging with
// register prefetch-1 (aligned 128-window tiles span <=2 adjacent levels).
// B: frag-major w1tf chunk staged contiguously; conflict-free ds_read_b128.
__launch_bounds__(512)
__attribute__((amdgpu_waves_per_eu(1, 4)))
__global__ void k2_scores(const u16* __restrict__ table, const u16* __restrict__ w1tf,
                          const float* __restrict__ b1, const float* __restrict__ w2,
                          const u16* __restrict__ widx, float* __restrict__ scores) {
  const int bid = blockIdx.x;
  const int xcd = bid & 7, q = bid >> 3;
  const int b = xcd * 4 + (q & 3), mt = q >> 2;
  __shared__ u16 Ts[128 * 64];     // two level slabs, swizzled, 16 KB
  __shared__ u16 Bs[8192];         // frag-major W1 chunk, contiguous, 16 KB
  __shared__ u16 widx_l[128];
  __shared__ float b1s[128], w2s[128];
  __shared__ float sc2[2][128];    // per-N-half partial scores
  int tid = threadIdx.x;
  if (tid < 128) {
    int n = mt * 128 + tid; if (n > NWIN - 1) n = NWIN - 1;  // pad-clamp
    widx_l[tid] = widx[n];
    b1s[tid] = b1[tid]; w2s[tid] = w2[tid];
  }
  __syncthreads();

  const int lv_lo = widx_l[0] >> 12;   // tile's lowest level (>=1); max lv_lo+1
  const u16* tb = table + (size_t)b * TLEV * S_ * H_ + (size_t)(lv_lo - 1) * S_ * H_;

  // Ts staging slots (1024 tasks / 512 thr = 2): t = tid, tid+512;
  // row = t>>3 in 0..127, c = t&7; swizzled dst = row*64 + ((c^(row&7))*8)
  int t0 = tid, t1 = tid + 512;
  int r0 = t0 >> 3, r1 = t1 >> 3;
  int c0 = t0 & 7,  c1 = t1 & 7;
  const u16* ts0 = tb + r0 * H_ + c0 * 8;
  const u16* ts1 = tb + r1 * H_ + c1 * 8;
  int sd0 = r0 * 64 + ((c0 ^ (r0 & 7)) * 8);
  int sd1 = r1 * 64 + ((c1 ^ (r1 & 7)) * 8);
  // Bs staging: 2 contiguous 16B copies per thread at u16 offsets
  // tid*8 and tid*8 + 4096 (same offset in chunk source and LDS dst).
  int bo0 = tid * 8, bo1 = bo0 + 4096;

  int wid = tid >> 6, lane = tid & 63;
  int wm = wid & 3, wn = wid >> 2;
  int lrow = lane & 15, quad = lane >> 4;

  // A-fragment addresses: windows m = wm*32 + mi*16 + lrow; {s,e2} x k2i
  int aoff[2][2][2];
#pragma unroll
  for (int mi = 0; mi < 2; ++mi) {
    int pk = widx_l[wm * 32 + mi * 16 + lrow];
    int s = pk & 63, e2 = (pk >> 6) & 63, lv = (pk >> 12) - lv_lo;  // 0 or 1
    int rs = lv * 64 + s, re = lv * 64 + e2;
#pragma unroll
    for (int k2i = 0; k2i < 2; ++k2i) {
      int c = quad + k2i * 4;
      aoff[mi][k2i][0] = rs * 64 + ((c ^ (rs & 7)) * 8);
      aoff[mi][k2i][1] = re * 64 + ((c ^ (re & 7)) * 8);
    }
  }

  uint4 rT0, rT1, rB0, rB1;

#define ISSUE(KC) do { \
  int kk_ = (KC) * 64; \
  const u16* wsrc_ = w1tf + (KC) * 8192; \
  rT0 = *reinterpret_cast<const uint4*>(ts0 + kk_); \
  rT1 = *reinterpret_cast<const uint4*>(ts1 + kk_); \
  rB0 = *reinterpret_cast<const uint4*>(wsrc_ + bo0); \
  rB1 = *reinterpret_cast<const uint4*>(wsrc_ + bo1); \
} while (0)

#define STAGE() do { \
  *reinterpret_cast<uint4*>(&Ts[sd0]) = rT0; \
  *reinterpret_cast<uint4*>(&Ts[sd1]) = rT1; \
  *reinterpret_cast<uint4*>(&Bs[bo0]) = rB0; \
  *reinterpret_cast<uint4*>(&Bs[bo1]) = rB1; \
} while (0)

  ISSUE(0);

  f32x4 acc[2][4];
#pragma unroll
  for (int mi = 0; mi < 2; ++mi)
#pragma unroll
    for (int j = 0; j < 4; ++j) acc[mi][j] = (f32x4){0.f, 0.f, 0.f, 0.f};

  for (int kc = 0; kc < 8; ++kc) {
    __syncthreads();   // previous chunk's fragment reads complete
    STAGE();
    __syncthreads();
    if (kc < 7) ISSUE(kc + 1);   // hides under the MFMA chunk below
#pragma unroll
    for (int k2i = 0; k2i < 2; ++k2i) {
      bf16x8 af[2];
#pragma unroll
      for (int mi = 0; mi < 2; ++mi) {
        uint4 va = *reinterpret_cast<const uint4*>(&Ts[aoff[mi][k2i][0]]);
        uint4 vb = *reinterpret_cast<const uint4*>(&Ts[aoff[mi][k2i][1]]);
        af[mi] = as_bf16x8(bfmax8(va, vb));
      }
      const u16* bk = &Bs[(k2i * 8 + wn * 4) * 512 + lane * 8];
#pragma unroll
      for (int j = 0; j < 4; ++j) {
        bf16x8 bfr = *reinterpret_cast<const bf16x8*>(bk + j * 512);
        acc[0][j] = __builtin_amdgcn_mfma_f32_16x16x32_bf16(af[0], bfr, acc[0][j], 0, 0, 0);
        acc[1][j] = __builtin_amdgcn_mfma_f32_16x16x32_bf16(af[1], bfr, acc[1][j], 0, 0, 0);
      }
    }
  }

#undef ISSUE
#undef STAGE

  // epilogue: score[m] = sum_n relu(hid+b1)*w2 (b2 dropped: softmax-invariant)
  // C layout: row = quad*4 + r, col = lrow (col n = wn*64 + j*16 + lrow).
  // Per-wave partial over its 64-att half -> sc2[wn][row]; combine after sync.
#pragma unroll
  for (int mi = 0; mi < 2; ++mi) {
#pragma unroll
    for (int r = 0; r < 4; ++r) {
      float p = 0.f;
#pragma unroll
      for (int j = 0; j < 4; ++j) {
        int n = wn * 64 + j * 16 + lrow;
        float v = acc[mi][j][r] + b1s[n];
        p += (v > 0.f ? v : 0.f) * w2s[n];
      }
      p += __shfl_xor(p, 1, 16);
      p += __shfl_xor(p, 2, 16);
      p += __shfl_xor(p, 4, 16);
      p += __shfl_xor(p, 8, 16);
      if (lrow == 0) sc2[wn][wm * 32 + mi * 16 + quad * 4 + r] = p;
    }
  }
  __syncthreads();
  if (tid < 128) {
    int nw = mt * 128 + tid;
    if (nw < NWIN) scores[b * NWIN + nw] = sc2[0][tid] + sc2[1][tid];
  }
}

// ========= k34: per-block softmax (redundant) + attn-weighted sum ==========
// grid 1024 (1D, XCD-swizzled: b = (bid&7)*4 + ((bid>>3)&3), hc = bid>>5),
// 256 thr; 16-wide h slice per block. Softmax recomputed per block; 1/sum
// folded into the final store. Table holds levels 1..6.
__launch_bounds__(256)
__global__ void k34_out(const u16* __restrict__ table, const float* __restrict__ scores,
                        const u16* __restrict__ widx, float* __restrict__ out) {
  int bid = blockIdx.x, tid = threadIdx.x;
  int xcd = bid & 7, q = bid >> 3;
  int b = xcd * 4 + (q & 3), hc = q >> 2;   // hc in 0..31
  __shared__ u16 Tl[6 * 64 * 16];       // 6 KB: levels 1..6, 16-col slice
  __shared__ float attn_l[NWIN];        // 8 KB, unnormalized exp
  __shared__ u16 widx_l[NWIN];          // 4 KB
  __shared__ float red[16][16];
  __shared__ float wredM[4], wredS[4];
  const u16* tb = table + (size_t)b * TLEV * S_ * H_;   // levels 1..6
  int h0 = hc * 16;
  int lane = tid & 63, wid = tid >> 6;

  for (int t = tid; t < 6 * 64 * 2; t += 256) {   // 768 tasks x 16 B
    int row = t >> 1, c = t & 1;
    uint4 v = *reinterpret_cast<const uint4*>(tb + row * H_ + h0 + c * 8);
    *reinterpret_cast<uint4*>(&Tl[row * 16 + c * 8]) = v;
  }
  for (int n = tid; n < NWIN; n += 256) widx_l[n] = widx[n];

  float mx = -1e30f;
  for (int n = tid; n < NWIN; n += 256) {
    float v = scores[b * NWIN + n];
    attn_l[n] = v;
    mx = fmaxf(mx, v);
  }
#pragma unroll
  for (int off = 32; off > 0; off >>= 1) mx = fmaxf(mx, __shfl_xor(mx, off, 64));
  if (lane == 0) wredM[wid] = mx;
  __syncthreads();   // also covers the Tl / widx_l / attn_l staging above
  mx = fmaxf(fmaxf(wredM[0], wredM[1]), fmaxf(wredM[2], wredM[3]));
  float sum = 0.f;
  for (int n = tid; n < NWIN; n += 256) {
    float e = __expf(attn_l[n] - mx);
    attn_l[n] = e;
    sum += e;
  }
#pragma unroll
  for (int off = 32; off > 0; off >>= 1) sum += __shfl_xor(sum, off, 64);
  if (lane == 0) wredS[wid] = sum;
  __syncthreads();
  float inv = 1.f / (wredS[0] + wredS[1] + wredS[2] + wredS[3]);

  int h = tid & 15, g = tid >> 4;   // 16 groups x 126 windows each
  float acc = 0.f;
  for (int n = g * 126; n < g * 126 + 126; ++n) {
    int pk = widx_l[n];
    int s = pk & 63, e2 = (pk >> 6) & 63, lv = pk >> 12;
    float va = bf2f(Tl[((lv - 1) * 64 + s) * 16 + h]);
    float vb = bf2f(Tl[((lv - 1) * 64 + e2) * 16 + h]);
    acc += attn_l[n] * fmaxf(va, vb);
  }
  red[g][h] = acc;
  __syncthreads();
  if (tid < 16) {
    float s2 = 0.f;
#pragma unroll
    for (int g2 = 0; g2 < 16; ++g2) s2 += red[g2][tid];
    out[b * H_ + h0 + tid] = s2 * inv;
  }
}

// ================================ launch ===================================
extern "C" void kernel_launch(void* const* d_in, const int* in_sizes, int n_in,
                              void* d_out, int out_size, void* d_ws, size_t ws_size,
                              hipStream_t stream) {
  const float* lstm = (const float*)d_in[0];
  const float* W1   = (const float*)d_in[1];
  const float* b1   = (const float*)d_in[2];
  const float* W2   = (const float*)d_in[3];
  // d_in[4] = b2: uniform shift ahead of softmax -> no output effect, unused.
  float* out = (float*)d_out;

  char* ws = (char*)d_ws;
  // ws layout: widx u16 [0,4096) | w1tf bf16 [4096,135168)
  //            | table bf16 levels 1..6 (12.58 MB) | scores f32 (258048 B)
  u16*   widx   = (u16*)(ws + 0);
  u16*   w1tf   = (u16*)(ws + 4096);
  u16*   table  = (u16*)(ws + 135168);
  float* scores = (float*)(ws + 12718080);

  k01_init <<<288, 256, 0, stream>>>(lstm, W1, table, w1tf, widx);
  k2_scores<<<512, 512, 0, stream>>>(table, w1tf, b1, W2, widx, scores);
  k34_out  <<<1024, 256, 0, stream>>>(table, scores, widx, out);
}